// Round 3
// baseline (8861.798 us; speedup 1.0000x reference)
//
#include <hip/hip_runtime.h>
#include <math.h>

#define BB 16
#define LL 4096
#define HH 128
#define NN2 32
#define NLAYERS 4
#define DOUTN 100
#define TWOH 256

// ---------------- transpose out_w (nl,2H,H) -> wT (nl,H,2H) ----------------
__global__ __launch_bounds__(256) void k_wT(const float* __restrict__ out_w, float* __restrict__ wT) {
    int idx = blockIdx.x * 256 + threadIdx.x;
    if (idx >= NLAYERS * TWOH * HH) return;
    int h = idx % HH;
    int o = (idx / HH) % TWOH;
    int i = idx / (HH * TWOH);
    wT[(i * HH + h) * TWOH + o] = out_w[idx];
}

// ---------------- encoder: h[b,h,l] = x[b,l]*enc_w[h] + enc_b[h] ----------------
__global__ __launch_bounds__(256) void k_enc(const float* __restrict__ x, const float* __restrict__ enc_w,
                                             const float* __restrict__ enc_b, float* __restrict__ hbuf) {
    int idx = blockIdx.x * 256 + threadIdx.x;       // over B*H*L/4
    int l4 = idx & (LL / 4 - 1);
    int h  = (idx / (LL / 4)) & (HH - 1);
    int b  = idx / (LL / 4 * HH);
    float4 xv = ((const float4*)(x + (size_t)b * LL))[l4];
    float w = enc_w[h], bb = enc_b[h];
    float4 o;
    o.x = fmaf(xv.x, w, bb);
    o.y = fmaf(xv.y, w, bb);
    o.z = fmaf(xv.z, w, bb);
    o.w = fmaf(xv.w, w, bb);
    ((float4*)(hbuf + ((size_t)b * HH + h) * LL))[l4] = o;
}

// ---------------- SSM scan, chunk-parallel, states in-thread ----------------
// One wave (64 lanes) per (b,h) row. Lane c owns time-chunk [c*64, c*64+64).
// All 32 modal states live in registers (fully unrolled arrays). No LDS, no
// per-step shuffles. Phase 1: local scan (zero init) -> chunk-final states.
// Combine: Hillis-Steele complex prefix over lanes with M = lambda^64.
// Phase 2: re-run seeded with true incoming state, emit y.
__global__ __launch_bounds__(64, 1) void k_scan(const float* __restrict__ u_, float* __restrict__ y_,
                                                const float* __restrict__ log_dt, const float* __restrict__ Cc,
                                                const float* __restrict__ log_A_real, const float* __restrict__ A_imag,
                                                int layer) {
    int row  = blockIdx.x;                 // b*H + h
    int h    = row & (HH - 1);
    int lane = threadIdx.x;                // chunk index 0..63
    const float* urow = u_ + (size_t)row * LL + lane * 64;
    float*       yrow = y_ + (size_t)row * LL + lane * 64;

    float dt = expf(log_dt[layer * HH + h]);
    float plr[NN2], pli[NN2], pc2r[NN2], pc2i[NN2], pmr[NN2], pmi[NN2];
#pragma unroll
    for (int n = 0; n < NN2; ++n) {
        int pidx = (layer * HH + h) * NN2 + n;
        float Ar  = -expf(log_A_real[pidx]);
        float Ai  = A_imag[pidx];
        float dAr = Ar * dt, dAi = Ai * dt;
        float el  = expf(dAr);
        float lr  = el * cosf(dAi);
        float li  = el * sinf(dAi);
        plr[n] = lr; pli[n] = li;
        float nr  = lr - 1.0f, ni = li;
        float inv = 1.0f / (Ar * Ar + Ai * Ai);
        float gr  = (nr * Ar + ni * Ai) * inv;
        float gi  = (ni * Ar - nr * Ai) * inv;
        float Cre = Cc[pidx * 2], Cim = Cc[pidx * 2 + 1];
        pc2r[n] = 2.0f * (Cre * gr - Cim * gi);
        pc2i[n] = 2.0f * (Cre * gi + Cim * gr);
        // M = lambda^64 in closed form
        float e64 = expf(dAr * 64.0f);
        float a64 = dAi * 64.0f;
        pmr[n] = e64 * cosf(a64);
        pmi[n] = e64 * sinf(a64);
    }

    float sr[NN2], si[NN2];
#pragma unroll
    for (int n = 0; n < NN2; ++n) { sr[n] = 0.0f; si[n] = 0.0f; }

    // ---- phase 1: local chunk scan (zero init), keep only final state ----
    float4 uv = *(const float4*)(urow);
#pragma unroll 1
    for (int s0 = 0; s0 < 64; s0 += 4) {
        int sn = s0 + 4 < 64 ? s0 + 4 : 60;
        float4 uvn = *(const float4*)(urow + sn);    // prefetch next group
        float us4[4] = {uv.x, uv.y, uv.z, uv.w};
#pragma unroll
        for (int j = 0; j < 4; ++j) {
            float u = us4[j];
#pragma unroll
            for (int n = 0; n < NN2; ++n) {
                float t   = fmaf(-pli[n], si[n], u);
                float nsi = fmaf(pli[n], sr[n], plr[n] * si[n]);
                sr[n] = fmaf(plr[n], sr[n], t);
                si[n] = nsi;
            }
        }
        uv = uvn;
    }

    // ---- combine: inclusive complex prefix v_c = sum_{j<=c} M^(c-j) b_j ----
    float mr[NN2], mi[NN2];
#pragma unroll
    for (int n = 0; n < NN2; ++n) { mr[n] = pmr[n]; mi[n] = pmi[n]; }
#pragma unroll
    for (int k = 1; k < 64; k <<= 1) {
#pragma unroll
        for (int n = 0; n < NN2; ++n) {
            float vr = __shfl_up(sr[n], k);
            float vi = __shfl_up(si[n], k);
            vr = (lane >= k) ? vr : 0.0f;
            vi = (lane >= k) ? vi : 0.0f;
            sr[n] = fmaf(mr[n], vr, fmaf(-mi[n], vi, sr[n]));
            si[n] = fmaf(mr[n], vi, fmaf(mi[n], vr, si[n]));
        }
#pragma unroll
        for (int n = 0; n < NN2; ++n) {
            float t = fmaf(mr[n], mr[n], -(mi[n] * mi[n]));
            mi[n] = 2.0f * mr[n] * mi[n];
            mr[n] = t;
        }
    }
    // shift by one lane: incoming state for this chunk
#pragma unroll
    for (int n = 0; n < NN2; ++n) {
        float vr = __shfl_up(sr[n], 1);
        float vi = __shfl_up(si[n], 1);
        sr[n] = (lane >= 1) ? vr : 0.0f;
        si[n] = (lane >= 1) ? vi : 0.0f;
    }

    // ---- phase 2: re-run with true incoming state, emit y ----
    uv = *(const float4*)(urow);
#pragma unroll 1
    for (int s0 = 0; s0 < 64; s0 += 4) {
        int sn = s0 + 4 < 64 ? s0 + 4 : 60;
        float4 uvn = *(const float4*)(urow + sn);
        float us4[4] = {uv.x, uv.y, uv.z, uv.w};
        float out4[4];
#pragma unroll
        for (int j = 0; j < 4; ++j) {
            float u = us4[j];
            float acc_a = 0.0f, acc_b = 0.0f;
#pragma unroll
            for (int n = 0; n < NN2; n += 2) {
                {
                    float t   = fmaf(-pli[n], si[n], u);
                    float nsi = fmaf(pli[n], sr[n], plr[n] * si[n]);
                    sr[n] = fmaf(plr[n], sr[n], t);
                    si[n] = nsi;
                    acc_a = fmaf(pc2r[n], sr[n], fmaf(-pc2i[n], si[n], acc_a));
                }
                {
                    int m = n + 1;
                    float t   = fmaf(-pli[m], si[m], u);
                    float nsi = fmaf(pli[m], sr[m], plr[m] * si[m]);
                    sr[m] = fmaf(plr[m], sr[m], t);
                    si[m] = nsi;
                    acc_b = fmaf(pc2r[m], sr[m], fmaf(-pc2i[m], si[m], acc_b));
                }
            }
            out4[j] = acc_a + acc_b;
        }
        *(float4*)(yrow + s0) = make_float4(out4[0], out4[1], out4[2], out4[3]);
        uv = uvn;
    }
}

// ---------------- conv(1x1 H->2H) + GLU + residual + LayerNorm, in-place on hbuf ----------------
__global__ __launch_bounds__(256) void k_conv(float* __restrict__ hbuf, const float* __restrict__ ybuf,
                                              const float* __restrict__ wT, const float* __restrict__ out_b,
                                              const float* __restrict__ Dp, const float* __restrict__ ln_g,
                                              const float* __restrict__ ln_b, int layer) {
    __shared__ float gs[HH][68];   // gelu(y + D*u), stride-68 pad (bank spread, float4-aligned)
    __shared__ float us[HH][68];   // residual u
    int tid = threadIdx.x;
    int blk = blockIdx.x;                 // B * (L/64)
    int b   = blk >> 6;
    int l0  = (blk & 63) << 6;
    const float* Drow = Dp + layer * HH;

    // load tile: 128 h x 64 l of y and u; apply D-skip + exact GELU
#pragma unroll
    for (int k = 0; k < 8; ++k) {
        int f  = tid + k * 256;           // 0..2047 (float4 index)
        int h  = f >> 4;
        int lq = f & 15;
        size_t base = ((size_t)(b * HH + h)) * LL + l0 + lq * 4;
        float4 yv = *(const float4*)(ybuf + base);
        float4 uv = *(const float4*)(hbuf + base);
        float d = Drow[h];
        float4 gv; float t;
        t = fmaf(d, uv.x, yv.x); gv.x = 0.5f * t * (1.0f + erff(t * 0.70710678118654752f));
        t = fmaf(d, uv.y, yv.y); gv.y = 0.5f * t * (1.0f + erff(t * 0.70710678118654752f));
        t = fmaf(d, uv.z, yv.z); gv.z = 0.5f * t * (1.0f + erff(t * 0.70710678118654752f));
        t = fmaf(d, uv.w, yv.w); gv.w = 0.5f * t * (1.0f + erff(t * 0.70710678118654752f));
        *(float4*)&us[h][lq * 4] = uv;
        *(float4*)&gs[h][lq * 4] = gv;
    }
    __syncthreads();

    // GEMM: y2[o, l] = sum_h wT[h][o] * gs[h][l]; thread = (ob = tid&63, lg = tid>>6)
    int ob = tid & 63;
    int lg = tid >> 6;
    float acc0[16], acc1[16], acc2[16], acc3[16];
#pragma unroll
    for (int j = 0; j < 16; ++j) { acc0[j] = 0.f; acc1[j] = 0.f; acc2[j] = 0.f; acc3[j] = 0.f; }
    const float* wrow = wT + layer * HH * TWOH;
#pragma unroll 2
    for (int h = 0; h < HH; ++h) {
        float w0 = wrow[h * TWOH + ob];
        float w1 = wrow[h * TWOH + ob + 64];
        float w2 = wrow[h * TWOH + ob + 128];
        float w3 = wrow[h * TWOH + ob + 192];
        float gvv[16];
        const float4* gp = (const float4*)&gs[h][lg * 16];
        *(float4*)&gvv[0]  = gp[0];
        *(float4*)&gvv[4]  = gp[1];
        *(float4*)&gvv[8]  = gp[2];
        *(float4*)&gvv[12] = gp[3];
#pragma unroll
        for (int j = 0; j < 16; ++j) {
            acc0[j] = fmaf(w0, gvv[j], acc0[j]);
            acc1[j] = fmaf(w1, gvv[j], acc1[j]);
            acc2[j] = fmaf(w2, gvv[j], acc2[j]);
            acc3[j] = fmaf(w3, gvv[j], acc3[j]);
        }
    }

    // bias + GLU (a = o<128, g = o>=128) + residual
    float bo0 = out_b[layer * TWOH + ob];
    float bo1 = out_b[layer * TWOH + ob + 64];
    float bo2 = out_b[layer * TWOH + ob + 128];
    float bo3 = out_b[layer * TWOH + ob + 192];
    int ch0 = ob, ch1 = ob + 64;
    float lg0 = ln_g[layer * HH + ch0], lb0 = ln_b[layer * HH + ch0];
    float lg1 = ln_g[layer * HH + ch1], lb1 = ln_b[layer * HH + ch1];
    float z0[16], z1[16];
#pragma unroll
    for (int j = 0; j < 16; ++j) {
        float a0 = acc0[j] + bo0;
        float a1 = acc1[j] + bo1;
        float g0 = acc2[j] + bo2;
        float g1 = acc3[j] + bo3;
        float s0 = 1.0f / (1.0f + expf(-g0));
        float s1 = 1.0f / (1.0f + expf(-g1));
        z0[j] = fmaf(a0, s0, us[ch0][lg * 16 + j]);
        z1[j] = fmaf(a1, s1, us[ch1][lg * 16 + j]);
    }

    // LayerNorm over the 128 channels (64 lanes x 2 channels, one wave per l-group)
#pragma unroll
    for (int j = 0; j < 16; ++j) {
        float s = z0[j] + z1[j];
        float q = z0[j] * z0[j] + z1[j] * z1[j];
        s += __shfl_xor(s, 32); q += __shfl_xor(q, 32);
        s += __shfl_xor(s, 16); q += __shfl_xor(q, 16);
        s += __shfl_xor(s, 8);  q += __shfl_xor(q, 8);
        s += __shfl_xor(s, 4);  q += __shfl_xor(q, 4);
        s += __shfl_xor(s, 2);  q += __shfl_xor(q, 2);
        s += __shfl_xor(s, 1);  q += __shfl_xor(q, 1);
        float mu  = s * (1.0f / 128.0f);
        float var = q * (1.0f / 128.0f) - mu * mu;
        float rs  = rsqrtf(var + 1e-5f);
        int l = l0 + lg * 16 + j;
        hbuf[((size_t)(b * HH + ch0)) * LL + l] = (z0[j] - mu) * rs * lg0 + lb0;
        hbuf[((size_t)(b * HH + ch1)) * LL + l] = (z1[j] - mu) * rs * lg1 + lb1;
    }
}

// ---------------- mean pool over L ----------------
__global__ __launch_bounds__(64) void k_pool(const float* __restrict__ hbuf, float* __restrict__ pooled) {
    int row = blockIdx.x;                 // B*H
    int t = threadIdx.x;                  // 64
    const float* p = hbuf + (size_t)row * LL;
    float s = 0.0f;
    for (int l = t; l < LL; l += 64) s += p[l];
    s += __shfl_xor(s, 32); s += __shfl_xor(s, 16); s += __shfl_xor(s, 8);
    s += __shfl_xor(s, 4);  s += __shfl_xor(s, 2);  s += __shfl_xor(s, 1);
    if (t == 0) pooled[row] = s * (1.0f / LL);
}

// ---------------- decoder ----------------
__global__ __launch_bounds__(256) void k_dec(const float* __restrict__ pooled, const float* __restrict__ dec_w,
                                             const float* __restrict__ dec_b, float* __restrict__ out) {
    int idx = blockIdx.x * 256 + threadIdx.x;
    if (idx >= BB * DOUTN) return;
    int o = idx % DOUTN;
    int b = idx / DOUTN;
    float s = dec_b[o];
    for (int h = 0; h < HH; ++h) s = fmaf(dec_w[o * HH + h], pooled[b * HH + h], s);
    out[idx] = s;
}

extern "C" void kernel_launch(void* const* d_in, const int* in_sizes, int n_in,
                              void* d_out, int out_size, void* d_ws, size_t ws_size,
                              hipStream_t stream) {
    const float* x          = (const float*)d_in[0];
    const float* enc_w      = (const float*)d_in[1];
    const float* enc_b      = (const float*)d_in[2];
    const float* log_dt     = (const float*)d_in[3];
    const float* C          = (const float*)d_in[4];
    const float* log_A_real = (const float*)d_in[5];
    const float* A_imag     = (const float*)d_in[6];
    const float* D          = (const float*)d_in[7];
    const float* out_w      = (const float*)d_in[8];
    const float* out_b      = (const float*)d_in[9];
    const float* ln_g       = (const float*)d_in[10];
    const float* ln_b       = (const float*)d_in[11];
    const float* dec_w      = (const float*)d_in[12];
    const float* dec_b      = (const float*)d_in[13];
    float* out = (float*)d_out;

    float* hbuf   = (float*)d_ws;                                  // B*H*L
    float* ybuf   = hbuf + (size_t)BB * HH * LL;                   // B*H*L
    float* wT     = ybuf + (size_t)BB * HH * LL;                   // NL*H*2H
    float* pooled = wT + (size_t)NLAYERS * HH * TWOH;              // B*H

    hipLaunchKernelGGL(k_wT, dim3((NLAYERS * TWOH * HH + 255) / 256), dim3(256), 0, stream, out_w, wT);
    hipLaunchKernelGGL(k_enc, dim3(BB * HH * LL / 4 / 256), dim3(256), 0, stream, x, enc_w, enc_b, hbuf);
    for (int layer = 0; layer < NLAYERS; ++layer) {
        hipLaunchKernelGGL(k_scan, dim3(BB * HH), dim3(64), 0, stream,
                           hbuf, ybuf, log_dt, C, log_A_real, A_imag, layer);
        hipLaunchKernelGGL(k_conv, dim3(BB * (LL / 64)), dim3(256), 0, stream,
                           hbuf, ybuf, wT, out_b, D, ln_g, ln_b, layer);
    }
    hipLaunchKernelGGL(k_pool, dim3(BB * HH), dim3(64), 0, stream, hbuf, pooled);
    hipLaunchKernelGGL(k_dec, dim3((BB * DOUTN + 255) / 256), dim3(256), 0, stream, pooled, dec_w, dec_b, out);
}

// Round 4
// 756.793 us; speedup vs baseline: 11.7097x; 11.7097x over previous
//
#include <hip/hip_runtime.h>
#include <math.h>

#define BB 16
#define LL 4096
#define HH 128
#define NN2 32
#define NHALF 16
#define CHUNK 128
#define NCHUNK 32
#define NLAYERS 4
#define DOUTN 100
#define TWOH 256

// ---------------- transpose out_w (nl,2H,H) -> wT (nl,H,2H) ----------------
__global__ __launch_bounds__(256) void k_wT(const float* __restrict__ out_w, float* __restrict__ wT) {
    int idx = blockIdx.x * 256 + threadIdx.x;
    if (idx >= NLAYERS * TWOH * HH) return;
    int h = idx % HH;
    int o = (idx / HH) % TWOH;
    int i = idx / (HH * TWOH);
    wT[(i * HH + h) * TWOH + o] = out_w[idx];
}

// ---------------- encoder: h[b,h,l] = x[b,l]*enc_w[h] + enc_b[h] ----------------
__global__ __launch_bounds__(256) void k_enc(const float* __restrict__ x, const float* __restrict__ enc_w,
                                             const float* __restrict__ enc_b, float* __restrict__ hbuf) {
    int idx = blockIdx.x * 256 + threadIdx.x;       // over B*H*L/4
    int l4 = idx & (LL / 4 - 1);
    int h  = (idx / (LL / 4)) & (HH - 1);
    int b  = idx / (LL / 4 * HH);
    float4 xv = ((const float4*)(x + (size_t)b * LL))[l4];
    float w = enc_w[h], bb = enc_b[h];
    float4 o;
    o.x = fmaf(xv.x, w, bb);
    o.y = fmaf(xv.y, w, bb);
    o.z = fmaf(xv.z, w, bb);
    o.w = fmaf(xv.w, w, bb);
    ((float4*)(hbuf + ((size_t)b * HH + h) * LL))[l4] = o;
}

// ---------------- SSM scan, chunk-parallel, 16 modes/lane ----------------
// One wave per (b,h) row. chunk = lane&31 (32 chunks x 128 steps),
// mode-half = lane>>5 (16 modes in registers per lane). Phase 1: local scan
// (zero init) -> chunk-final states. Combine: per-half Hillis-Steele complex
// prefix over 32 chunks with M = lambda^128 (closed form). Phase 2: re-run
// seeded with true incoming state; per-step output reduced across halves
// with one __shfl_xor(32).
__global__ __launch_bounds__(64, 2) void k_scan(const float* __restrict__ u_, float* __restrict__ y_,
                                                const float* __restrict__ log_dt, const float* __restrict__ Cc,
                                                const float* __restrict__ log_A_real, const float* __restrict__ A_imag,
                                                int layer) {
    int row   = blockIdx.x;                 // b*H + h
    int h     = row & (HH - 1);
    int lane  = threadIdx.x;
    int chunk = lane & 31;
    int half  = lane >> 5;
    const float* urow = u_ + (size_t)row * LL + chunk * CHUNK;
    float*       yrow = y_ + (size_t)row * LL + chunk * CHUNK;

    float dt = expf(log_dt[layer * HH + h]);
    float plr[NHALF], pli[NHALF], pc2r[NHALF], pc2i[NHALF], pmr[NHALF], pmi[NHALF];
#pragma unroll
    for (int n = 0; n < NHALF; ++n) {
        int pidx = (layer * HH + h) * NN2 + half * NHALF + n;
        float Ar  = -expf(log_A_real[pidx]);
        float Ai  = A_imag[pidx];
        float dAr = Ar * dt, dAi = Ai * dt;
        float el  = expf(dAr);
        float lr  = el * cosf(dAi);
        float li  = el * sinf(dAi);
        plr[n] = lr; pli[n] = li;
        float nr  = lr - 1.0f, ni = li;
        float inv = 1.0f / (Ar * Ar + Ai * Ai);
        float gr  = (nr * Ar + ni * Ai) * inv;
        float gi  = (ni * Ar - nr * Ai) * inv;
        float Cre = Cc[pidx * 2], Cim = Cc[pidx * 2 + 1];
        pc2r[n] = 2.0f * (Cre * gr - Cim * gi);
        pc2i[n] = 2.0f * (Cre * gi + Cim * gr);
        // M = lambda^CHUNK in closed form
        float eC = expf(dAr * (float)CHUNK);
        float aC = dAi * (float)CHUNK;
        pmr[n] = eC * cosf(aC);
        pmi[n] = eC * sinf(aC);
    }

    float sr[NHALF], si[NHALF];
#pragma unroll
    for (int n = 0; n < NHALF; ++n) { sr[n] = 0.0f; si[n] = 0.0f; }

    // ---- phase 1: local chunk scan (zero init), keep only final state ----
    float4 uv = *(const float4*)(urow);
#pragma unroll 1
    for (int s0 = 0; s0 < CHUNK; s0 += 4) {
        int sn = s0 + 4 < CHUNK ? s0 + 4 : CHUNK - 4;
        float4 uvn = *(const float4*)(urow + sn);    // prefetch next group
        float us4[4] = {uv.x, uv.y, uv.z, uv.w};
#pragma unroll
        for (int j = 0; j < 4; ++j) {
            float u = us4[j];
#pragma unroll
            for (int n = 0; n < NHALF; ++n) {
                float t   = fmaf(-pli[n], si[n], u);
                float nsi = fmaf(pli[n], sr[n], plr[n] * si[n]);
                sr[n] = fmaf(plr[n], sr[n], t);
                si[n] = nsi;
            }
        }
        uv = uvn;
    }

    // ---- combine: inclusive complex prefix over 32 chunks (per half) ----
    {
        float mr[NHALF], mi[NHALF];
#pragma unroll
        for (int n = 0; n < NHALF; ++n) { mr[n] = pmr[n]; mi[n] = pmi[n]; }
#pragma unroll
        for (int k = 1; k < NCHUNK; k <<= 1) {
#pragma unroll
            for (int n = 0; n < NHALF; ++n) {
                float vr = __shfl_up(sr[n], k);
                float vi = __shfl_up(si[n], k);
                vr = (chunk >= k) ? vr : 0.0f;
                vi = (chunk >= k) ? vi : 0.0f;
                sr[n] = fmaf(mr[n], vr, fmaf(-mi[n], vi, sr[n]));
                si[n] = fmaf(mr[n], vi, fmaf(mi[n], vr, si[n]));
            }
#pragma unroll
            for (int n = 0; n < NHALF; ++n) {
                float t = fmaf(mr[n], mr[n], -(mi[n] * mi[n]));
                mi[n] = 2.0f * mr[n] * mi[n];
                mr[n] = t;
            }
        }
        // shift by one chunk: incoming state for this chunk
#pragma unroll
        for (int n = 0; n < NHALF; ++n) {
            float vr = __shfl_up(sr[n], 1);
            float vi = __shfl_up(si[n], 1);
            sr[n] = (chunk >= 1) ? vr : 0.0f;
            si[n] = (chunk >= 1) ? vi : 0.0f;
        }
    }

    // ---- phase 2: re-run with true incoming state, emit y ----
    uv = *(const float4*)(urow);
#pragma unroll 1
    for (int s0 = 0; s0 < CHUNK; s0 += 4) {
        int sn = s0 + 4 < CHUNK ? s0 + 4 : CHUNK - 4;
        float4 uvn = *(const float4*)(urow + sn);
        float us4[4] = {uv.x, uv.y, uv.z, uv.w};
        float out4[4];
#pragma unroll
        for (int j = 0; j < 4; ++j) {
            float u = us4[j];
            float acc_a = 0.0f, acc_b = 0.0f;
#pragma unroll
            for (int n = 0; n < NHALF; n += 2) {
                {
                    float t   = fmaf(-pli[n], si[n], u);
                    float nsi = fmaf(pli[n], sr[n], plr[n] * si[n]);
                    sr[n] = fmaf(plr[n], sr[n], t);
                    si[n] = nsi;
                    acc_a = fmaf(pc2r[n], sr[n], fmaf(-pc2i[n], si[n], acc_a));
                }
                {
                    int m = n + 1;
                    float t   = fmaf(-pli[m], si[m], u);
                    float nsi = fmaf(pli[m], sr[m], plr[m] * si[m]);
                    sr[m] = fmaf(plr[m], sr[m], t);
                    si[m] = nsi;
                    acc_b = fmaf(pc2r[m], sr[m], fmaf(-pc2i[m], si[m], acc_b));
                }
            }
            out4[j] = acc_a + acc_b;
        }
        // reduce across the two mode-halves
        out4[0] += __shfl_xor(out4[0], 32);
        out4[1] += __shfl_xor(out4[1], 32);
        out4[2] += __shfl_xor(out4[2], 32);
        out4[3] += __shfl_xor(out4[3], 32);
        if (half == 0) *(float4*)(yrow + s0) = make_float4(out4[0], out4[1], out4[2], out4[3]);
        uv = uvn;
    }
}

// ---------------- conv(1x1 H->2H) + GLU + residual + LayerNorm, in-place on hbuf ----------------
__global__ __launch_bounds__(256) void k_conv(float* __restrict__ hbuf, const float* __restrict__ ybuf,
                                              const float* __restrict__ wT, const float* __restrict__ out_b,
                                              const float* __restrict__ Dp, const float* __restrict__ ln_g,
                                              const float* __restrict__ ln_b, int layer) {
    __shared__ float gs[HH][68];   // gelu(y + D*u), stride-68 pad (bank spread, float4-aligned)
    __shared__ float us[HH][68];   // residual u
    int tid = threadIdx.x;
    int blk = blockIdx.x;                 // B * (L/64)
    int b   = blk >> 6;
    int l0  = (blk & 63) << 6;
    const float* Drow = Dp + layer * HH;

    // load tile: 128 h x 64 l of y and u; apply D-skip + exact GELU
#pragma unroll
    for (int k = 0; k < 8; ++k) {
        int f  = tid + k * 256;           // 0..2047 (float4 index)
        int h  = f >> 4;
        int lq = f & 15;
        size_t base = ((size_t)(b * HH + h)) * LL + l0 + lq * 4;
        float4 yv = *(const float4*)(ybuf + base);
        float4 uv = *(const float4*)(hbuf + base);
        float d = Drow[h];
        float4 gv; float t;
        t = fmaf(d, uv.x, yv.x); gv.x = 0.5f * t * (1.0f + erff(t * 0.70710678118654752f));
        t = fmaf(d, uv.y, yv.y); gv.y = 0.5f * t * (1.0f + erff(t * 0.70710678118654752f));
        t = fmaf(d, uv.z, yv.z); gv.z = 0.5f * t * (1.0f + erff(t * 0.70710678118654752f));
        t = fmaf(d, uv.w, yv.w); gv.w = 0.5f * t * (1.0f + erff(t * 0.70710678118654752f));
        *(float4*)&us[h][lq * 4] = uv;
        *(float4*)&gs[h][lq * 4] = gv;
    }
    __syncthreads();

    // GEMM: y2[o, l] = sum_h wT[h][o] * gs[h][l]; thread = (ob = tid&63, lg = tid>>6)
    int ob = tid & 63;
    int lg = tid >> 6;
    float acc0[16], acc1[16], acc2[16], acc3[16];
#pragma unroll
    for (int j = 0; j < 16; ++j) { acc0[j] = 0.f; acc1[j] = 0.f; acc2[j] = 0.f; acc3[j] = 0.f; }
    const float* wrow = wT + layer * HH * TWOH;
#pragma unroll 2
    for (int h = 0; h < HH; ++h) {
        float w0 = wrow[h * TWOH + ob];
        float w1 = wrow[h * TWOH + ob + 64];
        float w2 = wrow[h * TWOH + ob + 128];
        float w3 = wrow[h * TWOH + ob + 192];
        float gvv[16];
        const float4* gp = (const float4*)&gs[h][lg * 16];
        *(float4*)&gvv[0]  = gp[0];
        *(float4*)&gvv[4]  = gp[1];
        *(float4*)&gvv[8]  = gp[2];
        *(float4*)&gvv[12] = gp[3];
#pragma unroll
        for (int j = 0; j < 16; ++j) {
            acc0[j] = fmaf(w0, gvv[j], acc0[j]);
            acc1[j] = fmaf(w1, gvv[j], acc1[j]);
            acc2[j] = fmaf(w2, gvv[j], acc2[j]);
            acc3[j] = fmaf(w3, gvv[j], acc3[j]);
        }
    }

    // bias + GLU (a = o<128, g = o>=128) + residual
    float bo0 = out_b[layer * TWOH + ob];
    float bo1 = out_b[layer * TWOH + ob + 64];
    float bo2 = out_b[layer * TWOH + ob + 128];
    float bo3 = out_b[layer * TWOH + ob + 192];
    int ch0 = ob, ch1 = ob + 64;
    float lg0 = ln_g[layer * HH + ch0], lb0 = ln_b[layer * HH + ch0];
    float lg1 = ln_g[layer * HH + ch1], lb1 = ln_b[layer * HH + ch1];
    float z0[16], z1[16];
#pragma unroll
    for (int j = 0; j < 16; ++j) {
        float a0 = acc0[j] + bo0;
        float a1 = acc1[j] + bo1;
        float g0 = acc2[j] + bo2;
        float g1 = acc3[j] + bo3;
        float s0 = 1.0f / (1.0f + expf(-g0));
        float s1 = 1.0f / (1.0f + expf(-g1));
        z0[j] = fmaf(a0, s0, us[ch0][lg * 16 + j]);
        z1[j] = fmaf(a1, s1, us[ch1][lg * 16 + j]);
    }

    // LayerNorm over the 128 channels (64 lanes x 2 channels, one wave per l-group)
#pragma unroll
    for (int j = 0; j < 16; ++j) {
        float s = z0[j] + z1[j];
        float q = z0[j] * z0[j] + z1[j] * z1[j];
        s += __shfl_xor(s, 32); q += __shfl_xor(q, 32);
        s += __shfl_xor(s, 16); q += __shfl_xor(q, 16);
        s += __shfl_xor(s, 8);  q += __shfl_xor(q, 8);
        s += __shfl_xor(s, 4);  q += __shfl_xor(q, 4);
        s += __shfl_xor(s, 2);  q += __shfl_xor(q, 2);
        s += __shfl_xor(s, 1);  q += __shfl_xor(q, 1);
        float mu  = s * (1.0f / 128.0f);
        float var = q * (1.0f / 128.0f) - mu * mu;
        float rs  = rsqrtf(var + 1e-5f);
        int l = l0 + lg * 16 + j;
        hbuf[((size_t)(b * HH + ch0)) * LL + l] = (z0[j] - mu) * rs * lg0 + lb0;
        hbuf[((size_t)(b * HH + ch1)) * LL + l] = (z1[j] - mu) * rs * lg1 + lb1;
    }
}

// ---------------- mean pool over L ----------------
__global__ __launch_bounds__(64) void k_pool(const float* __restrict__ hbuf, float* __restrict__ pooled) {
    int row = blockIdx.x;                 // B*H
    int t = threadIdx.x;                  // 64
    const float* p = hbuf + (size_t)row * LL;
    float s = 0.0f;
    for (int l = t; l < LL; l += 64) s += p[l];
    s += __shfl_xor(s, 32); s += __shfl_xor(s, 16); s += __shfl_xor(s, 8);
    s += __shfl_xor(s, 4);  s += __shfl_xor(s, 2);  s += __shfl_xor(s, 1);
    if (t == 0) pooled[row] = s * (1.0f / LL);
}

// ---------------- decoder ----------------
__global__ __launch_bounds__(256) void k_dec(const float* __restrict__ pooled, const float* __restrict__ dec_w,
                                             const float* __restrict__ dec_b, float* __restrict__ out) {
    int idx = blockIdx.x * 256 + threadIdx.x;
    if (idx >= BB * DOUTN) return;
    int o = idx % DOUTN;
    int b = idx / DOUTN;
    float s = dec_b[o];
    for (int h = 0; h < HH; ++h) s = fmaf(dec_w[o * HH + h], pooled[b * HH + h], s);
    out[idx] = s;
}

extern "C" void kernel_launch(void* const* d_in, const int* in_sizes, int n_in,
                              void* d_out, int out_size, void* d_ws, size_t ws_size,
                              hipStream_t stream) {
    const float* x          = (const float*)d_in[0];
    const float* enc_w      = (const float*)d_in[1];
    const float* enc_b      = (const float*)d_in[2];
    const float* log_dt     = (const float*)d_in[3];
    const float* C          = (const float*)d_in[4];
    const float* log_A_real = (const float*)d_in[5];
    const float* A_imag     = (const float*)d_in[6];
    const float* D          = (const float*)d_in[7];
    const float* out_w      = (const float*)d_in[8];
    const float* out_b      = (const float*)d_in[9];
    const float* ln_g       = (const float*)d_in[10];
    const float* ln_b       = (const float*)d_in[11];
    const float* dec_w      = (const float*)d_in[12];
    const float* dec_b      = (const float*)d_in[13];
    float* out = (float*)d_out;

    float* hbuf   = (float*)d_ws;                                  // B*H*L
    float* ybuf   = hbuf + (size_t)BB * HH * LL;                   // B*H*L
    float* wT     = ybuf + (size_t)BB * HH * LL;                   // NL*H*2H
    float* pooled = wT + (size_t)NLAYERS * HH * TWOH;              // B*H

    hipLaunchKernelGGL(k_wT, dim3((NLAYERS * TWOH * HH + 255) / 256), dim3(256), 0, stream, out_w, wT);
    hipLaunchKernelGGL(k_enc, dim3(BB * HH * LL / 4 / 256), dim3(256), 0, stream, x, enc_w, enc_b, hbuf);
    for (int layer = 0; layer < NLAYERS; ++layer) {
        hipLaunchKernelGGL(k_scan, dim3(BB * HH), dim3(64), 0, stream,
                           hbuf, ybuf, log_dt, C, log_A_real, A_imag, layer);
        hipLaunchKernelGGL(k_conv, dim3(BB * (LL / 64)), dim3(256), 0, stream,
                           hbuf, ybuf, wT, out_b, D, ln_g, ln_b, layer);
    }
    hipLaunchKernelGGL(k_pool, dim3(BB * HH), dim3(64), 0, stream, hbuf, pooled);
    hipLaunchKernelGGL(k_dec, dim3((BB * DOUTN + 255) / 256), dim3(256), 0, stream, pooled, dec_w, dec_b, out);
}